// Round 1
// baseline (90.665 us; speedup 1.0000x reference)
//
#include <hip/hip_runtime.h>
#include <math.h>

#define B 96
#define D 512
#define DPAD 97   // LDS leading-dim pad: 96 % 32 == 0 would alias all rows to one bank
#define MARGIN_TRIPLE 0.2f
#define MARGIN_INTER  0.1f

// Kernel 1: dot[i][j] = <emb_i, emb_j>, one block per row i.
__global__ __launch_bounds__(256)
void bhq_dots(const float* __restrict__ embs, float* __restrict__ dot) {
    __shared__ float ei[D];
    const int i   = blockIdx.x;
    const int tid = threadIdx.x;
    for (int k = tid; k < D; k += 256) ei[k] = embs[i * D + k];
    __syncthreads();
    const int wave = tid >> 6;
    const int lane = tid & 63;
    for (int j = wave; j < B; j += 4) {
        const float* ej = embs + j * D;
        float s = 0.f;
#pragma unroll
        for (int m = 0; m < D / 64; ++m) {
            const int k = lane + m * 64;
            s += ei[k] * ej[k];
        }
#pragma unroll
        for (int off = 32; off > 0; off >>= 1) s += __shfl_xor(s, off, 64);
        if (lane == 0) dot[i * B + j] = s;
    }
}

// Kernel 2: distances + batch-hard mining + collapsed O(B^2) quadruplet term.
__global__ __launch_bounds__(256)
void bhq_mine(const float* __restrict__ dot, const int* __restrict__ idty,
              float* __restrict__ out) {
    __shared__ float ds[B][DPAD];
    __shared__ float sq[B];
    __shared__ int   y[B];
    __shared__ float hp_s[B], hn_s[B];
    __shared__ int   p_s[B], n_s[B], haspos_s[B];
    __shared__ float wsum[4];

    const int tid = threadIdx.x;
    if (tid < B) {
        sq[tid] = dot[tid * B + tid];
        y[tid]  = idty[tid];
    }
    __syncthreads();

    // d = sqrt(max(sq_i - 2 dot + sq_j, 0)), with exact-zero handling like ref
    for (int idx = tid; idx < B * B; idx += 256) {
        const int i = idx / B, j = idx - i * B;
        float v = sq[i] - 2.f * dot[idx] + sq[j];
        v = fmaxf(v, 0.f);
        ds[i][j] = (v == 0.f) ? 0.f : sqrtf(v);
    }
    __syncthreads();

    // Per-row batch-hard mining (threads 0..95), matching jnp first-occurrence ties.
    if (tid < B) {
        const int r  = tid;
        const int yr = y[r];
        float maxd = -INFINITY;
        for (int j = 0; j < B; ++j) maxd = fmaxf(maxd, ds[r][j]);

        float hp = -INFINITY; int p = 0; int haspos = 0;
        for (int j = 0; j < B; ++j) {
            const bool pos = (j != r) && (y[j] == yr);
            haspos |= (int)pos;
            const float ap = pos ? ds[r][j] : 0.f;   // ap_dist = mask * d
            if (ap > hp) { hp = ap; p = j; }          // argmax, first occurrence
        }
        float hn = INFINITY; int n = 0;
        for (int j = 0; j < B; ++j) {
            const float an = ds[r][j] + ((y[j] == yr) ? maxd : 0.f); // d + max_d*(1-ne)
            if (an < hn) { hn = an; n = j; }          // argmin, first occurrence
        }
        hp_s[r] = hp; hn_s[r] = hn; p_s[r] = p; n_s[r] = n; haspos_s[r] = haspos;
    }
    __syncthreads();

    // triplet term (per row) + collapsed inter-class term (per (x,l))
    float tloc = 0.f;
    if (tid < B) tloc = fmaxf(hp_s[tid] - hn_s[tid] + MARGIN_TRIPLE, 0.f);

    float iloc = 0.f;
    for (int idx = tid; idx < B * B; idx += 256) {
        const int x = idx / B, l = idx - x * B;
        const int p = p_s[x], n = n_s[x];
        const int yp = y[p], yn = y[n], yl = y[l];
        // qmask collapsed: need y_p!=y_n, y_l!=y_n, y_l!=y_p, and class(p) size >= 2
        if (yp != yn && haspos_s[p] && yl != yp && yl != yn) {
            iloc += fmaxf(hp_s[p] - ds[n][l] + MARGIN_INTER, 0.f);
        }
    }

    float v = tloc * (1.f / B) + iloc * (1.f / (B * B));
#pragma unroll
    for (int off = 32; off > 0; off >>= 1) v += __shfl_xor(v, off, 64);
    if ((tid & 63) == 0) wsum[tid >> 6] = v;
    __syncthreads();
    if (tid == 0) {
        float s = wsum[0] + wsum[1] + wsum[2] + wsum[3];
        out[0] = s;
    }
}

extern "C" void kernel_launch(void* const* d_in, const int* in_sizes, int n_in,
                              void* d_out, int out_size, void* d_ws, size_t ws_size,
                              hipStream_t stream) {
    const float* embs = (const float*)d_in[0];
    const int*   idty = (const int*)d_in[1];
    float*       out  = (float*)d_out;
    float*       dot  = (float*)d_ws;   // B*B floats = 36 KiB scratch

    bhq_dots<<<B, 256, 0, stream>>>(embs, dot);
    bhq_mine<<<1, 256, 0, stream>>>(dot, idty, out);
}

// Round 2
// 83.842 us; speedup vs baseline: 1.0814x; 1.0814x over previous
//
#include <hip/hip_runtime.h>
#include <math.h>

#define B 96
#define D 512
#define MARGIN_TRIPLE 0.2f
#define MARGIN_INTER  0.1f

// Kernel 1: one block per row i. Streams all emb_j once, computing
// dot(i,j) and ||e_j||^2 from the same loads -> distance row -> in-block
// batch-hard mining (wave-wide argmax/argmin, first-occurrence ties).
__global__ __launch_bounds__(256)
void bhq_rows(const float* __restrict__ embs, const int* __restrict__ idty,
              float* __restrict__ wsD, float* __restrict__ wsHP,
              float* __restrict__ wsHN, int* __restrict__ wsP,
              int* __restrict__ wsN, int* __restrict__ wsHas) {
    __shared__ float ei[D];
    __shared__ float drow[B];
    __shared__ int   y[B];
    __shared__ float ssred[4];

    const int i    = blockIdx.x;
    const int tid  = threadIdx.x;
    const int wave = tid >> 6;
    const int lane = tid & 63;

    // load row i into LDS, fused ||e_i||^2 partial
    float ss = 0.f;
    for (int k = tid; k < D; k += 256) {
        float v = embs[i * D + k];
        ei[k] = v;
        ss += v * v;
    }
#pragma unroll
    for (int off = 32; off > 0; off >>= 1) ss += __shfl_xor(ss, off, 64);
    if (lane == 0) ssred[wave] = ss;
    if (tid < B) y[tid] = idty[tid];
    __syncthreads();
    const float ssi = ssred[0] + ssred[1] + ssred[2] + ssred[3];

    // distance row: d(i,j) = sqrt(max(||ei||^2 + ||ej||^2 - 2<ei,ej>, 0))
    for (int j = wave; j < B; j += 4) {
        const float* ej = embs + j * D;
        float s = 0.f, s2 = 0.f;
#pragma unroll
        for (int m = 0; m < D / 64; ++m) {
            float a = ei[lane + m * 64];
            float b = ej[lane + m * 64];
            s  += a * b;
            s2 += b * b;
        }
#pragma unroll
        for (int off = 32; off > 0; off >>= 1) {
            s  += __shfl_xor(s,  off, 64);
            s2 += __shfl_xor(s2, off, 64);
        }
        if (lane == 0) {
            float v = fmaxf(ssi + s2 - 2.f * s, 0.f);
            drow[j] = (j == i || v == 0.f) ? 0.f : sqrtf(v);  // exact-0 diag like ref
        }
    }
    __syncthreads();

    // wave 0: batch-hard mining over the 96-element row
    if (wave == 0) {
        const int  yr   = y[i];
        const int  j0   = lane, j1 = lane + 64;
        const bool has1 = (lane < 32);
        const float d0 = drow[j0];
        const float d1 = has1 ? drow[j1] : 0.f;
        const int   y0 = y[j0];
        const int   y1 = has1 ? y[j1] : -1;

        // max_d over the full row
        float mx = fmaxf(d0, has1 ? d1 : -INFINITY);
#pragma unroll
        for (int off = 32; off > 0; off >>= 1) mx = fmaxf(mx, __shfl_xor(mx, off, 64));

        // hardest positive: argmax over ap = pos ? d : 0 (first occurrence)
        const bool pos0 = (j0 != i) && (y0 == yr);
        const bool pos1 = has1 && (j1 != i) && (y1 == yr);
        float a0 = pos0 ? d0 : 0.f;
        float a1 = has1 ? (pos1 ? d1 : 0.f) : -INFINITY;
        float bv; int bi;
        if (a1 > a0) { bv = a1; bi = j1; } else { bv = a0; bi = j0; }
#pragma unroll
        for (int off = 32; off > 0; off >>= 1) {
            float ov = __shfl_xor(bv, off, 64);
            int   oi = __shfl_xor(bi, off, 64);
            if (ov > bv || (ov == bv && oi < bi)) { bv = ov; bi = oi; }
        }

        // hardest negative: argmin over an = d + (same-id ? max_d : 0) (first occurrence)
        float n0 = d0 + ((y0 == yr) ? mx : 0.f);
        float n1 = has1 ? (d1 + ((y1 == yr) ? mx : 0.f)) : INFINITY;
        float cv; int ci;
        if (n1 < n0) { cv = n1; ci = j1; } else { cv = n0; ci = j0; }
#pragma unroll
        for (int off = 32; off > 0; off >>= 1) {
            float ov = __shfl_xor(cv, off, 64);
            int   oi = __shfl_xor(ci, off, 64);
            if (ov < cv || (ov == cv && oi < ci)) { cv = ov; ci = oi; }
        }

        unsigned long long bal = __ballot(pos0 || pos1);
        if (lane == 0) {
            wsHP[i]  = bv;
            wsHN[i]  = cv;
            wsP[i]   = bi;
            wsN[i]   = ci;
            wsHas[i] = (bal != 0ULL) ? 1 : 0;
        }
    }
    if (tid < B) wsD[i * B + tid] = drow[tid];
}

// Kernel 2: tiny O(B^2) final reduce (collapsed quadruplet term + triplet mean)
__global__ __launch_bounds__(256)
void bhq_final(const float* __restrict__ wsD, const float* __restrict__ wsHP,
               const float* __restrict__ wsHN, const int* __restrict__ wsP,
               const int* __restrict__ wsN, const int* __restrict__ wsHas,
               const int* __restrict__ idty, float* __restrict__ out) {
    __shared__ float hp[B], hn[B];
    __shared__ int   p[B], n[B], has[B], y[B];
    __shared__ float wsum[4];
    const int tid = threadIdx.x;
    if (tid < B) {
        hp[tid]  = wsHP[tid];
        hn[tid]  = wsHN[tid];
        p[tid]   = wsP[tid];
        n[tid]   = wsN[tid];
        has[tid] = wsHas[tid];
        y[tid]   = idty[tid];
    }
    __syncthreads();

    float acc = 0.f;
    if (tid < B) acc = fmaxf(hp[tid] - hn[tid] + MARGIN_TRIPLE, 0.f) * (1.f / B);

    float il = 0.f;
    for (int idx = tid; idx < B * B; idx += 256) {
        const int x = idx / B, l = idx - x * B;
        const int px = p[x], nx = n[x];
        const int yp = y[px], yn = y[nx], yl = y[l];
        // qmask collapsed: y_p!=y_n, y_l!=y_p, y_l!=y_n, class(p) has >=2 members
        if (yp != yn && has[px] && yl != yp && yl != yn) {
            il += fmaxf(hp[px] - wsD[nx * B + l] + MARGIN_INTER, 0.f);
        }
    }
    acc += il * (1.f / (B * B));

#pragma unroll
    for (int off = 32; off > 0; off >>= 1) acc += __shfl_xor(acc, off, 64);
    if ((tid & 63) == 0) wsum[tid >> 6] = acc;
    __syncthreads();
    if (tid == 0) out[0] = wsum[0] + wsum[1] + wsum[2] + wsum[3];
}

extern "C" void kernel_launch(void* const* d_in, const int* in_sizes, int n_in,
                              void* d_out, int out_size, void* d_ws, size_t ws_size,
                              hipStream_t stream) {
    const float* embs = (const float*)d_in[0];
    const int*   idty = (const int*)d_in[1];
    float*       out  = (float*)d_out;

    float* wsD   = (float*)d_ws;        // B*B floats
    float* wsHP  = wsD + B * B;
    float* wsHN  = wsHP + B;
    int*   wsP   = (int*)(wsHN + B);
    int*   wsN   = wsP + B;
    int*   wsHas = wsN + B;

    bhq_rows<<<B, 256, 0, stream>>>(embs, idty, wsD, wsHP, wsHN, wsP, wsN, wsHas);
    bhq_final<<<1, 256, 0, stream>>>(wsD, wsHP, wsHN, wsP, wsN, wsHas, idty, out);
}